// Round 2
// baseline (104.309 us; speedup 1.0000x reference)
//
#include <hip/hip_runtime.h>

// Weighted 2D Procrustes (Kabsch) with z-padding == closed-form 2x2 polar factor.
// B=1024 batches, N=4096 points. Output: R [B,3,3] then t [B,3,1], fp32.
//
// All moment accumulation + the det-sign decision are done in fp64 so the
// rotation-vs-reflection branch (sign(det A)) can never flip due to fp32
// accumulation noise on near-degenerate batches (independent random clouds
// make |det A| ~ 0 likely for ~1 of 1024 batches at fp32 noise scale).

constexpr int BATCH = 1024;
constexpr int NPTS  = 4096;
constexpr double EPSV = 1e-4;

__device__ __forceinline__ double wredd(double v) {
    #pragma unroll
    for (int off = 1; off < 64; off <<= 1) v += __shfl_xor(v, off, 64);
    return v;
}

__global__ __launch_bounds__(256) void procrustes_kernel(
    const float* __restrict__ src, const float* __restrict__ tgt,
    const float* __restrict__ wts, float* __restrict__ out)
{
    const int b   = blockIdx.x;
    const int tid = threadIdx.x;
    const float* sb = src + (size_t)b * (NPTS * 2);
    const float* tb = tgt + (size_t)b * (NPTS * 2);
    const float* wb = wts + (size_t)b * NPTS;

    // acc: 0=sum_w 1=sum w*sx 2=sum w*sy 3=sum w*tx 4=sum w*ty
    //      5=sum w*tx*sx 6=sum w*tx*sy 7=sum w*ty*sx 8=sum w*ty*sy
    double acc[9] = {0,0,0,0,0,0,0,0,0};

    // 2 points per iteration: float4 coord loads (16B/lane, coalesced), float2 weights.
    for (int i = tid * 2; i < NPTS; i += 512) {
        const float4 s2 = *reinterpret_cast<const float4*>(sb + 2 * i);
        const float4 t2 = *reinterpret_cast<const float4*>(tb + 2 * i);
        const float2 w2 = *reinterpret_cast<const float2*>(wb + i);
        {
            const double w  = (double)w2.x;
            const double sx = (double)s2.x, sy = (double)s2.y;
            const double tx = (double)t2.x, ty = (double)t2.y;
            acc[0] += w;
            acc[1] += w * sx; acc[2] += w * sy;
            acc[3] += w * tx; acc[4] += w * ty;
            const double wt0 = w * tx, wt1 = w * ty;
            acc[5] += wt0 * sx; acc[6] += wt0 * sy;
            acc[7] += wt1 * sx; acc[8] += wt1 * sy;
        }
        {
            const double w  = (double)w2.y;
            const double sx = (double)s2.z, sy = (double)s2.w;
            const double tx = (double)t2.z, ty = (double)t2.w;
            acc[0] += w;
            acc[1] += w * sx; acc[2] += w * sy;
            acc[3] += w * tx; acc[4] += w * ty;
            const double wt0 = w * tx, wt1 = w * ty;
            acc[5] += wt0 * sx; acc[6] += wt0 * sy;
            acc[7] += wt1 * sx; acc[8] += wt1 * sy;
        }
    }

    // wave64 butterfly reduce, then cross-wave via LDS (4 waves).
    #pragma unroll
    for (int k = 0; k < 9; ++k) acc[k] = wredd(acc[k]);

    __shared__ double red[4][9];
    const int lane = tid & 63, wave = tid >> 6;
    if (lane == 0) {
        #pragma unroll
        for (int k = 0; k < 9; ++k) red[wave][k] = acc[k];
    }
    __syncthreads();

    if (tid == 0) {
        double s[9];
        #pragma unroll
        for (int k = 0; k < 9; ++k)
            s[k] = red[0][k] + red[1][k] + red[2][k] + red[3][k];

        const double w   = s[0] + EPSV;
        const double inv = 1.0 / w;
        const double scx = s[1] * inv, scy = s[2] * inv;   // src centroid (z=0)
        const double tcx = s[3] * inv, tcy = s[4] * inv;   // tgt centroid (z=0)

        // 2x2 cross-covariance up to positive scale (polar factor is scale-invariant):
        // A_ij = sum w*t_i*s_j - (sum w*t_i)(sum w*s_j)/w
        const double a00 = s[5] - s[3] * s[1] * inv;
        const double a01 = s[6] - s[3] * s[2] * inv;
        const double a10 = s[7] - s[4] * s[1] * inv;
        const double a11 = s[8] - s[4] * s[2] * inv;

        const double p = 0.5 * (a00 + a11);   // rotation part:   p*I + q*J
        const double q = 0.5 * (a10 - a01);
        const double r = 0.5 * (a00 - a11);   // reflection part: r*K + t*L
        const double t = 0.5 * (a01 + a10);

        const double rot2 = p * p + q * q;
        const double ref2 = r * r + t * t;    // det A = rot2 - ref2

        double R00, R01, R10, R11, Rzz;
        if (rot2 >= ref2) {                   // det(A) >= 0: closest rotation
            const double n = rsqrt(fmax(rot2, 1e-300));
            R00 =  p * n; R01 = -q * n;
            R10 =  q * n; R11 =  p * n;
            Rzz = 1.0;
        } else {                              // det(A) < 0: closest reflection, Rzz=-1
            const double n = rsqrt(fmax(ref2, 1e-300));
            R00 =  r * n; R01 =  t * n;
            R10 =  t * n; R11 = -r * n;
            Rzz = -1.0;
        }

        // t1 = src_c - R^T tgt_c ; t2 = -R t1   (z components are exactly 0)
        const double t1x = scx - (R00 * tcx + R10 * tcy);
        const double t1y = scy - (R01 * tcx + R11 * tcy);
        const double t2x = -(R00 * t1x + R01 * t1y);
        const double t2y = -(R10 * t1x + R11 * t1y);

        float* Ro = out + (size_t)b * 9;
        Ro[0] = (float)R00; Ro[1] = (float)R01; Ro[2] = 0.0f;
        Ro[3] = (float)R10; Ro[4] = (float)R11; Ro[5] = 0.0f;
        Ro[6] = 0.0f;       Ro[7] = 0.0f;       Ro[8] = (float)Rzz;

        float* To = out + (size_t)BATCH * 9 + (size_t)b * 3;
        To[0] = (float)t2x; To[1] = (float)t2y; To[2] = 0.0f;
    }
}

extern "C" void kernel_launch(void* const* d_in, const int* in_sizes, int n_in,
                              void* d_out, int out_size, void* d_ws, size_t ws_size,
                              hipStream_t stream) {
    const float* src = (const float*)d_in[0];
    const float* tgt = (const float*)d_in[1];
    const float* wts = (const float*)d_in[2];
    float* out = (float*)d_out;
    procrustes_kernel<<<BATCH, 256, 0, stream>>>(src, tgt, wts, out);
}

// Round 3
// 102.846 us; speedup vs baseline: 1.0142x; 1.0142x over previous
//
#include <hip/hip_runtime.h>

// Weighted 2D Procrustes (Kabsch) with z-padding == closed-form 2x2 polar factor.
// B=1024 batches, N=4096 points. Output: R [B,3,3] then t [B,3,1], fp32.
//
// Moments + det-sign decision in fp64 (det A ties within fp32 noise occur for
// ~1/1024 random batches — fp32 accumulation flipped the Rzz branch in R1).
// R3: all loads are 16 B/lane (float4 weights, 4 pts/iter), fp64 math shaped
// as fma (8 fma + 2 mul + 1 add per point) so DP VALU (~5 us) hides under the
// 12.7 us HBM stream.

constexpr int BATCH = 1024;
constexpr int NPTS  = 4096;
constexpr double EPSV = 1e-4;

__device__ __forceinline__ double wredd(double v) {
    #pragma unroll
    for (int off = 1; off < 64; off <<= 1) v += __shfl_xor(v, off, 64);
    return v;
}

__global__ __launch_bounds__(256) void procrustes_kernel(
    const float* __restrict__ src, const float* __restrict__ tgt,
    const float* __restrict__ wts, float* __restrict__ out)
{
    const int b   = blockIdx.x;
    const int tid = threadIdx.x;
    const float* sb = src + (size_t)b * (NPTS * 2);
    const float* tb = tgt + (size_t)b * (NPTS * 2);
    const float* wb = wts + (size_t)b * NPTS;

    // acc: 0=sum_w 1=sum w*sx 2=sum w*sy 3=sum w*tx 4=sum w*ty
    //      5=sum w*tx*sx 6=sum w*tx*sy 7=sum w*ty*sx 8=sum w*ty*sy
    double acc[9] = {0,0,0,0,0,0,0,0,0};

    // 4 points per iteration; every load is a 16-byte float4.
    #pragma unroll
    for (int pass = 0; pass < NPTS / 1024; ++pass) {
        const int i = tid * 4 + pass * 1024;
        const float4 wv  = *reinterpret_cast<const float4*>(wb + i);
        const float4 sa  = *reinterpret_cast<const float4*>(sb + 2 * i);
        const float4 sc  = *reinterpret_cast<const float4*>(sb + 2 * i + 4);
        const float4 ta  = *reinterpret_cast<const float4*>(tb + 2 * i);
        const float4 tc  = *reinterpret_cast<const float4*>(tb + 2 * i + 4);

        const float wf[4] = {wv.x, wv.y, wv.z, wv.w};
        const float sxf[4] = {sa.x, sa.z, sc.x, sc.z};
        const float syf[4] = {sa.y, sa.w, sc.y, sc.w};
        const float txf[4] = {ta.x, ta.z, tc.x, tc.z};
        const float tyf[4] = {ta.y, ta.w, tc.y, tc.w};

        #pragma unroll
        for (int j = 0; j < 4; ++j) {
            const double w  = (double)wf[j];
            const double sx = (double)sxf[j], sy = (double)syf[j];
            const double tx = (double)txf[j], ty = (double)tyf[j];
            acc[0] += w;
            acc[1] = fma(w, sx, acc[1]);
            acc[2] = fma(w, sy, acc[2]);
            acc[3] = fma(w, tx, acc[3]);
            acc[4] = fma(w, ty, acc[4]);
            const double wt0 = w * tx, wt1 = w * ty;   // exact: 24bx24b fits fp64
            acc[5] = fma(wt0, sx, acc[5]);
            acc[6] = fma(wt0, sy, acc[6]);
            acc[7] = fma(wt1, sx, acc[7]);
            acc[8] = fma(wt1, sy, acc[8]);
        }
    }

    // wave64 butterfly reduce, then cross-wave via LDS (4 waves).
    #pragma unroll
    for (int k = 0; k < 9; ++k) acc[k] = wredd(acc[k]);

    __shared__ double red[4][9];
    const int lane = tid & 63, wave = tid >> 6;
    if (lane == 0) {
        #pragma unroll
        for (int k = 0; k < 9; ++k) red[wave][k] = acc[k];
    }
    __syncthreads();

    if (tid == 0) {
        double s[9];
        #pragma unroll
        for (int k = 0; k < 9; ++k)
            s[k] = red[0][k] + red[1][k] + red[2][k] + red[3][k];

        const double w   = s[0] + EPSV;
        const double inv = 1.0 / w;
        const double scx = s[1] * inv, scy = s[2] * inv;   // src centroid (z=0)
        const double tcx = s[3] * inv, tcy = s[4] * inv;   // tgt centroid (z=0)

        // 2x2 cross-covariance up to positive scale (polar factor is scale-invariant):
        // A_ij = sum w*t_i*s_j - (sum w*t_i)(sum w*s_j)/w
        const double a00 = s[5] - s[3] * s[1] * inv;
        const double a01 = s[6] - s[3] * s[2] * inv;
        const double a10 = s[7] - s[4] * s[1] * inv;
        const double a11 = s[8] - s[4] * s[2] * inv;

        const double p = 0.5 * (a00 + a11);   // rotation part:   p*I + q*J
        const double q = 0.5 * (a10 - a01);
        const double r = 0.5 * (a00 - a11);   // reflection part: r*K + t*L
        const double t = 0.5 * (a01 + a10);

        const double rot2 = p * p + q * q;
        const double ref2 = r * r + t * t;    // det A = rot2 - ref2

        double R00, R01, R10, R11, Rzz;
        if (rot2 >= ref2) {                   // det(A) >= 0: closest rotation
            const double n = rsqrt(fmax(rot2, 1e-300));
            R00 =  p * n; R01 = -q * n;
            R10 =  q * n; R11 =  p * n;
            Rzz = 1.0;
        } else {                              // det(A) < 0: closest reflection, Rzz=-1
            const double n = rsqrt(fmax(ref2, 1e-300));
            R00 =  r * n; R01 =  t * n;
            R10 =  t * n; R11 = -r * n;
            Rzz = -1.0;
        }

        // t1 = src_c - R^T tgt_c ; t2 = -R t1   (z components are exactly 0)
        const double t1x = scx - (R00 * tcx + R10 * tcy);
        const double t1y = scy - (R01 * tcx + R11 * tcy);
        const double t2x = -(R00 * t1x + R01 * t1y);
        const double t2y = -(R10 * t1x + R11 * t1y);

        float* Ro = out + (size_t)b * 9;
        Ro[0] = (float)R00; Ro[1] = (float)R01; Ro[2] = 0.0f;
        Ro[3] = (float)R10; Ro[4] = (float)R11; Ro[5] = 0.0f;
        Ro[6] = 0.0f;       Ro[7] = 0.0f;       Ro[8] = (float)Rzz;

        float* To = out + (size_t)BATCH * 9 + (size_t)b * 3;
        To[0] = (float)t2x; To[1] = (float)t2y; To[2] = 0.0f;
    }
}

extern "C" void kernel_launch(void* const* d_in, const int* in_sizes, int n_in,
                              void* d_out, int out_size, void* d_ws, size_t ws_size,
                              hipStream_t stream) {
    const float* src = (const float*)d_in[0];
    const float* tgt = (const float*)d_in[1];
    const float* wts = (const float*)d_in[2];
    float* out = (float*)d_out;
    procrustes_kernel<<<BATCH, 256, 0, stream>>>(src, tgt, wts, out);
}